// Round 5
// baseline (31.338 us; speedup 1.0000x reference)
//
#include <hip/hip_runtime.h>
#include <hip/hip_bf16.h>

// Segment-mean over sorted indexes — single dispatch, (token, D-third) waves.
// hidden: [B=8, S=2048, D=768] f32; ori_indexes: [B, S] sorted int (<T=1024)
// out:    [B, T, D] f32 = segment_sum / clip(count,1)
//
// Work item = one wave = (batch b, token t, D-third j). D=768 = 3*256 floats,
// so a wave reads/writes exactly 64 lanes x float4 = 1KB per row — perfect
// coalescing. 24576 work items = 3x the chip's 8192-wave residency, so block
// backfill smooths the per-CU Binomial token-size tail that a 1x-resident
// static grid (R3) cannot (R3 ended on the worst CU, ~+36% over mean).
// Sorted indexes -> token rows = [lower_bound(t), lower_bound(t+1)) via two
// wave-uniform L1-resident binary searches (proven ~free in R1).
// Every output element written exactly once (empty tokens write 0) ->
// deterministic, no pre-zeroing, no workspace.

#define SGA_B 8
#define SGA_S 2048
#define SGA_D 768
#define SGA_T 1024
#define SGA_NV (SGA_D / 4)   // 192 float4 per row; third = 64 float4 = 1KB

typedef float f32x4 __attribute__((ext_vector_type(4)));

__global__ __launch_bounds__(256) void sga_segmean_kernel(
    const float* __restrict__ hidden,
    const int* __restrict__ idx,
    float* __restrict__ out) {
    // global wave-sized work id, ordered (b, t, j) with j fastest
    const int W = blockIdx.x * 4 + (threadIdx.x >> 6);   // 0..24575
    const int lane = threadIdx.x & 63;

    const int bt = W / 3;            // (b*1024 + t)
    const int j = W - 3 * bt;        // D-third 0..2
    const int b = bt >> 10;
    const int t = bt & (SGA_T - 1);

    const int* __restrict__ ib = idx + b * SGA_S;

    // lower_bound(t), then lower_bound(t+1) continuing from it (wave-uniform)
    int lo = 0, hi = SGA_S;
    while (lo < hi) { int m = (lo + hi) >> 1; if (ib[m] < t) lo = m + 1; else hi = m; }
    const int s0 = lo;
    hi = SGA_S;
    while (lo < hi) { int m = (lo + hi) >> 1; if (ib[m] < t + 1) lo = m + 1; else hi = m; }
    const int s1 = lo;

    const f32x4* __restrict__ hbase =
        reinterpret_cast<const f32x4*>(hidden) + (size_t)b * SGA_S * SGA_NV + j * 64 + lane;

    f32x4 a0 = (f32x4)0.f, a1 = (f32x4)0.f;

    int s = s0;
    for (; s + 1 < s1; s += 2) {
        const f32x4* r0 = hbase + (size_t)s * SGA_NV;
        f32x4 v0 = __builtin_nontemporal_load(r0);
        f32x4 v1 = __builtin_nontemporal_load(r0 + SGA_NV);
        a0 += v0; a1 += v1;
    }
    if (s < s1) {
        a0 += __builtin_nontemporal_load(hbase + (size_t)s * SGA_NV);
    }
    a0 += a1;

    const int cnt = s1 - s0;
    const float inv = (cnt > 0) ? (1.0f / (float)cnt) : 0.0f;
    a0 *= inv;

    f32x4* __restrict__ o =
        reinterpret_cast<f32x4*>(out) + ((size_t)bt) * SGA_NV + j * 64 + lane;
    __builtin_nontemporal_store(a0, o);
}

extern "C" void kernel_launch(void* const* d_in, const int* in_sizes, int n_in,
                              void* d_out, int out_size, void* d_ws, size_t ws_size,
                              hipStream_t stream) {
    const float* hidden = (const float*)d_in[0];
    const int* idx = (const int*)d_in[1];
    float* out = (float*)d_out;

    // 24576 wave-work-items / 4 waves per block = 6144 blocks
    dim3 grid((SGA_B * SGA_T * 3) / 4, 1, 1);
    sga_segmean_kernel<<<grid, dim3(256, 1, 1), 0, stream>>>(hidden, idx, out);
}